// Round 1
// baseline (438.934 us; speedup 1.0000x reference)
//
#include <hip/hip_runtime.h>
#include <hip/hip_bf16.h>

#define BATCH 16
#define CIN   512
#define CMID  256
#define HWN   4096

typedef __bf16 bf16x8  __attribute__((ext_vector_type(8)));
typedef float  floatx4 __attribute__((ext_vector_type(4)));
typedef int    intx4   __attribute__((ext_vector_type(4)));

__device__ __forceinline__ unsigned short f2bf(float f){
  union { float f; unsigned int u; } v; v.f = f;
  unsigned int u = v.u;
  unsigned int r = u + 0x7FFFu + ((u >> 16) & 1u);   // RTNE
  return (unsigned short)(r >> 16);
}

__device__ __forceinline__ float bsum(float v, float* scr, int t){
  #pragma unroll
  for (int o = 32; o >= 1; o >>= 1) v += __shfl_xor(v, o, 64);
  __syncthreads();
  if ((t & 63) == 0) scr[t >> 6] = v;
  __syncthreads();
  return scr[0] + scr[1] + scr[2] + scr[3];
}

__device__ __forceinline__ float bmax(float v, float* scr, int t){
  #pragma unroll
  for (int o = 32; o >= 1; o >>= 1) v = fmaxf(v, __shfl_xor(v, o, 64));
  __syncthreads();
  if ((t & 63) == 0) scr[t >> 6] = v;
  __syncthreads();
  return fmaxf(fmaxf(scr[0], scr[1]), fmaxf(scr[2], scr[3]));
}

// ---------------- K0: w_ql fp32 -> bf16 ----------------
__global__ __launch_bounds__(256) void k0_convert(const float* __restrict__ w,
                                                  unsigned short* __restrict__ wbf){
  int i = blockIdx.x * 256 + threadIdx.x;
  wbf[i] = f2bf(w[i]);
}

// ---------------- K1: bf16 MFMA GEMM g_x = w_ql * x, keep row-max; fused fp32 qr ----
// grid (64 ntiles, 16 b), 256 threads. Tile: M=256 (all), N=64, K=32 per iter.
__global__ __launch_bounds__(256) void k1_gemm(
    const float* __restrict__ x, const unsigned short* __restrict__ wbf,
    const float* __restrict__ w_qr, float* __restrict__ qr, float* __restrict__ gpart)
{
  __shared__ __align__(16) unsigned short Alds[CMID * 32];   // [m][k] 16 KB
  __shared__ __align__(16) unsigned short Blds[64 * 32];     // [n][k] 4 KB (x^T)
  __shared__ float wqr_s[CIN];

  const int t = threadIdx.x;
  const int ntile = blockIdx.x;
  const int b = blockIdx.y;
  const int n0 = ntile * 64;
  const int lane = t & 63, wave = t >> 6;
  const int grp  = t >> 2;        // 0..63 : A-row-within-issue / B-n
  const int koff = (t & 3) * 8;   // 0,8,16,24

  wqr_s[t] = w_qr[t];
  wqr_s[t + 256] = w_qr[t + 256];

  const float* xb = x + (size_t)b * CIN * HWN;

  floatx4 acc[4][4];
  #pragma unroll
  for (int i = 0; i < 4; ++i)
    #pragma unroll
    for (int j = 0; j < 4; ++j)
      acc[i][j] = (floatx4){0.f, 0.f, 0.f, 0.f};

  float qa = 0.f;
  __syncthreads();

  for (int kt = 0; kt < 16; ++kt){
    const int k0 = kt * 32;
    // stage A (bf16 w_ql): 4 issues of 16B/lane, row-major [m][32k]
    #pragma unroll
    for (int q = 0; q < 4; ++q){
      const int m = q * 64 + grp;
      *(intx4*)(&Alds[m * 32 + koff]) = *(const intx4*)(&wbf[m * CIN + k0 + koff]);
    }
    // stage B: load 8 strided fp32, fuse qr partial (fp32), convert, one b128 write
    float xv[8];
    #pragma unroll
    for (int j = 0; j < 8; ++j)
      xv[j] = xb[(size_t)(k0 + koff + j) * HWN + n0 + grp];
    #pragma unroll
    for (int j = 0; j < 8; ++j)
      qa = fmaf(wqr_s[k0 + koff + j], xv[j], qa);
    union { unsigned short u[8]; intx4 v; } pk;
    #pragma unroll
    for (int j = 0; j < 8; ++j) pk.u[j] = f2bf(xv[j]);
    *(intx4*)(&Blds[grp * 32 + koff]) = pk.v;
    __syncthreads();

    bf16x8 af[4], bfr[4];
    #pragma unroll
    for (int ms = 0; ms < 4; ++ms)
      af[ms]  = *(const bf16x8*)(&Alds[(wave*64 + ms*16 + (lane & 15))*32 + (lane >> 4)*8]);
    #pragma unroll
    for (int ns = 0; ns < 4; ++ns)
      bfr[ns] = *(const bf16x8*)(&Blds[(ns*16 + (lane & 15))*32 + (lane >> 4)*8]);
    #pragma unroll
    for (int ms = 0; ms < 4; ++ms)
      #pragma unroll
      for (int ns = 0; ns < 4; ++ns)
        acc[ms][ns] = __builtin_amdgcn_mfma_f32_16x16x32_bf16(af[ms], bfr[ns], acc[ms][ns], 0, 0, 0);
    __syncthreads();
  }

  // qr: reduce the 4 k-phase lanes of each n
  qa += __shfl_xor(qa, 1, 64);
  qa += __shfl_xor(qa, 2, 64);
  if ((t & 3) == 0) qr[b * HWN + n0 + grp] = qa;

  // per-m max over this tile's 64 pixels (4 n-subtiles, then 16 cols via shuffle)
  #pragma unroll
  for (int ms = 0; ms < 4; ++ms){
    #pragma unroll
    for (int r = 0; r < 4; ++r){
      float v = fmaxf(fmaxf(acc[ms][0][r], acc[ms][1][r]),
                      fmaxf(acc[ms][2][r], acc[ms][3][r]));
      v = fmaxf(v, __shfl_xor(v, 1, 64));
      v = fmaxf(v, __shfl_xor(v, 2, 64));
      v = fmaxf(v, __shfl_xor(v, 4, 64));
      v = fmaxf(v, __shfl_xor(v, 8, 64));
      if ((lane & 15) == 0){
        const int m = wave*64 + ms*16 + (lane >> 4)*4 + r;
        gpart[((b*64 + ntile) * CMID) + m] = v;
      }
    }
  }
}

// ---------------- K2: per-b: gmax->avg softmax, wmix = avg^T w_vl, qr softmax stats ----
__global__ __launch_bounds__(256) void k2_small(
    const float* __restrict__ gpart, const float* __restrict__ b_ql,
    const float* __restrict__ w_vl, const float* __restrict__ qr,
    float* __restrict__ wmix, float* __restrict__ stats)
{
  __shared__ float scr[4];
  __shared__ float avg_s[CMID];
  const int b = blockIdx.x, t = threadIdx.x;

  float gm = -3.0e38f;
  for (int nt = 0; nt < 64; ++nt)
    gm = fmaxf(gm, gpart[(b*64 + nt) * CMID + t]);
  gm += b_ql[t];

  float mx = bmax(gm, scr, t);
  float e = expf(gm - mx);
  float s = bsum(e, scr, t);
  avg_s[t] = e / s;
  __syncthreads();

  float w0 = 0.f, w1 = 0.f;
  for (int m = 0; m < CMID; ++m){
    float a = avg_s[m];
    w0 = fmaf(a, w_vl[m*CIN + t], w0);
    w1 = fmaf(a, w_vl[m*CIN + t + 256], w1);
  }
  wmix[b*CIN + t] = w0;
  wmix[b*CIN + t + 256] = w1;

  const float* qb = qr + b*HWN;
  float qm = -3.0e38f;
  for (int i = t; i < HWN; i += 256) qm = fmaxf(qm, qb[i]);
  qm = bmax(qm, scr, t);
  float qs = 0.f;
  for (int i = t; i < HWN; i += 256) qs += expf(qb[i] - qm);
  qs = bsum(qs, scr, t);
  if (t == 0){ stats[b] = qm; stats[16 + b] = qs; }
}

// ---------------- K3: one pass over x: xmask[b,c]=sum_h x*mask ; ctx[b,h]=sum_c wmix*x ----
// grid (32 htiles, 4 ctiles, 16 b); 128x128 tile; thread (i=t>>4, j=t&15) owns 8c x 8h.
__global__ __launch_bounds__(256) void k3_dual(
    const float* __restrict__ x, const float* __restrict__ qr,
    const float* __restrict__ stats, const float* __restrict__ wmix,
    float* __restrict__ xmask, float* __restrict__ ctx)
{
  const int ht = blockIdx.x, ct = blockIdx.y, b = blockIdx.z;
  const int t = threadIdx.x;
  const int i = t >> 4, j = t & 15;
  const int c0 = ct * 128, h0 = ht * 128;
  const float* xb = x + (size_t)b * CIN * HWN;
  const float qm = stats[b], inv_qs = 1.0f / stats[16 + b];

  float maskv[8], wmv[8];
  #pragma unroll
  for (int l = 0; l < 8; ++l)
    maskv[l] = expf(qr[b*HWN + h0 + j + 16*l] - qm) * inv_qs;
  #pragma unroll
  for (int k = 0; k < 8; ++k)
    wmv[k] = wmix[b*CIN + c0 + i + 16*k];

  float xm[8] = {0,0,0,0,0,0,0,0};
  float cx[8] = {0,0,0,0,0,0,0,0};
  #pragma unroll
  for (int k = 0; k < 8; ++k){
    const float* row = xb + (size_t)(c0 + i + 16*k) * HWN + h0 + j;
    float v[8];
    #pragma unroll
    for (int l = 0; l < 8; ++l) v[l] = row[16*l];
    #pragma unroll
    for (int l = 0; l < 8; ++l){
      xm[k] = fmaf(v[l], maskv[l], xm[k]);
      cx[l] = fmaf(v[l], wmv[k], cx[l]);
    }
  }
  // xmask: reduce over j (lane bits 0..3)
  #pragma unroll
  for (int k = 0; k < 8; ++k){
    float v = xm[k];
    v += __shfl_xor(v, 1, 64); v += __shfl_xor(v, 2, 64);
    v += __shfl_xor(v, 4, 64); v += __shfl_xor(v, 8, 64);
    if (j == 0) atomicAdd(&xmask[b*CIN + c0 + i + 16*k], v);
  }
  // ctx: reduce over i within wave (lane bits 4..5), atomic per wave
  #pragma unroll
  for (int l = 0; l < 8; ++l){
    float v = cx[l];
    v += __shfl_xor(v, 16, 64); v += __shfl_xor(v, 32, 64);
    if (((t & 63) >> 4) == 0) atomicAdd(&ctx[b*HWN + h0 + j + 16*l], v);
  }
}

// ---------------- K4: per-b channel tail + sk-attn + spatial softmax -> P, Q, sp ----
__global__ __launch_bounds__(256) void k4_tail(
    const float* __restrict__ xmask, const float* __restrict__ w_vr, const float* __restrict__ b_vr,
    const float* __restrict__ w_up, const float* __restrict__ b_up,
    const float* __restrict__ ln_g, const float* __restrict__ ln_b,
    const float* __restrict__ w_red, const float* __restrict__ bn_g, const float* __restrict__ bn_b,
    const float* __restrict__ bn_rm, const float* __restrict__ bn_rv,
    const float* __restrict__ w_sel, const float* __restrict__ ctxg,
    float* __restrict__ P, float* __restrict__ Q, float* __restrict__ sp)
{
  __shared__ float scr[4];
  __shared__ float xm_s[CIN];
  __shared__ float cm_s[CMID];
  __shared__ float ch_s[CIN];
  __shared__ float red_s[32];
  const int b = blockIdx.x, t = threadIdx.x;

  xm_s[t] = xmask[b*CIN + t];
  xm_s[t + 256] = xmask[b*CIN + t + 256];
  __syncthreads();

  // context[m], m = t
  float cacc = b_vr[t];
  const float* wr = w_vr + (size_t)t * CIN;
  for (int c = 0; c < CIN; ++c) cacc = fmaf(wr[c], xm_s[c], cacc);
  cm_s[t] = cacc;
  __syncthreads();

  // up[o], o = t and t+256
  float up0 = b_up[t], up1 = b_up[t + 256];
  const float* wu0 = w_up + (size_t)t * CMID;
  const float* wu1 = w_up + (size_t)(t + 256) * CMID;
  for (int m = 0; m < CMID; ++m){
    up0 = fmaf(wu0[m], cm_s[m], up0);
    up1 = fmaf(wu1[m], cm_s[m], up1);
  }
  // LayerNorm over 512
  float mu = bsum(up0 + up1, scr, t) * (1.0f / 512.0f);
  float d0 = up0 - mu, d1 = up1 - mu;
  float var = bsum(d0*d0 + d1*d1, scr, t) * (1.0f / 512.0f);
  float rstd = rsqrtf(var + 1e-5f);
  float ch0 = 1.f / (1.f + expf(-(d0 * rstd * ln_g[t] + ln_b[t])));
  float ch1 = 1.f / (1.f + expf(-(d1 * rstd * ln_g[t + 256] + ln_b[t + 256])));
  ch_s[t] = ch0; ch_s[t + 256] = ch1;
  __syncthreads();

  // red[a] from closed-form s[c] = ch*(1+1/HW) + 1/HW
  {
    const int a = t >> 3, sub = t & 7;
    float r = 0.f;
    const float* wrd = w_red + a * CIN;
    const float k1 = 1.0f + 1.0f/4096.0f, k2 = 1.0f/4096.0f;
    for (int c = sub; c < CIN; c += 8) r = fmaf(wrd[c], fmaf(ch_s[c], k1, k2), r);
    r += __shfl_xor(r, 1, 64); r += __shfl_xor(r, 2, 64); r += __shfl_xor(r, 4, 64);
    if (sub == 0){
      float bn = (r - bn_rm[a]) * rsqrtf(bn_rv[a] + 1e-5f) * bn_g[a] + bn_b[a];
      red_s[a] = fmaxf(bn, 0.0f);
    }
  }
  __syncthreads();

  // sel -> 2-way softmax -> P, Q  (c = t, t+256)
  #pragma unroll
  for (int q = 0; q < 2; ++q){
    const int c = t + q * 256;
    float s0 = 0.f, s1 = 0.f;
    const float* ws0 = w_sel + (size_t)c * 32;
    const float* ws1 = w_sel + (size_t)(CIN + c) * 32;
    #pragma unroll
    for (int a = 0; a < 32; ++a){
      s0 = fmaf(ws0[a], red_s[a], s0);
      s1 = fmaf(ws1[a], red_s[a], s1);
    }
    float a0 = 1.f / (1.f + expf(s1 - s0));   // sigmoid(s0-s1)
    float a1 = 1.f - a0;
    float ch = ch_s[c];
    P[b*CIN + c] = 1.0f + a1 * ch;
    Q[b*CIN + c] = a0 * ch + a1;
  }

  // spatial softmax -> sp
  const float* cb = ctxg + b * HWN;
  float cm = -3.0e38f;
  for (int h = t; h < HWN; h += 256) cm = fmaxf(cm, cb[h]);
  cm = bmax(cm, scr, t);
  float cs = 0.f;
  for (int h = t; h < HWN; h += 256) cs += expf(cb[h] - cm);
  cs = bsum(cs, scr, t);
  const float inv = 1.0f / cs;
  for (int h = t; h < HWN; h += 256) sp[b*HWN + h] = expf(cb[h] - cm) * inv;
}

// ---------------- K5: out = x * (P + sp * Q), one block per (b,c) row ----------------
__global__ __launch_bounds__(256) void k5_out(
    const float* __restrict__ x, const float* __restrict__ P, const float* __restrict__ Q,
    const float* __restrict__ sp, float* __restrict__ out)
{
  const int bc = blockIdx.x;          // b*512 + c
  const int b = bc >> 9;
  const int t = threadIdx.x;
  const float p = P[bc], q = Q[bc];
  const floatx4* xr = (const floatx4*)(x + (size_t)bc * HWN);
  const floatx4* sr = (const floatx4*)(sp + (size_t)b * HWN);
  floatx4* outr = (floatx4*)(out + (size_t)bc * HWN);
  #pragma unroll
  for (int r = 0; r < 4; ++r){
    const int idx = t + r * 256;
    floatx4 xv = xr[idx];
    floatx4 sv = sr[idx];
    outr[idx] = xv * (p + sv * q);
  }
}

extern "C" void kernel_launch(void* const* d_in, const int* in_sizes, int n_in,
                              void* d_out, int out_size, void* d_ws, size_t ws_size,
                              hipStream_t stream)
{
  (void)in_sizes; (void)n_in; (void)out_size; (void)ws_size;
  const float* x    = (const float*)d_in[0];
  const float* w_qr = (const float*)d_in[1];
  // d_in[2] = b_qr : softmax-invariant, unused
  const float* w_vr = (const float*)d_in[3];
  const float* b_vr = (const float*)d_in[4];
  const float* w_up = (const float*)d_in[5];
  const float* b_up = (const float*)d_in[6];
  const float* ln_g = (const float*)d_in[7];
  const float* ln_b = (const float*)d_in[8];
  const float* w_ql = (const float*)d_in[9];
  const float* b_ql = (const float*)d_in[10];
  const float* w_vl = (const float*)d_in[11];
  // d_in[12] = b_vl : softmax-invariant, unused
  const float* w_red = (const float*)d_in[13];
  const float* bn_g  = (const float*)d_in[14];
  const float* bn_b  = (const float*)d_in[15];
  const float* bn_rm = (const float*)d_in[16];
  const float* bn_rv = (const float*)d_in[17];
  const float* w_sel = (const float*)d_in[18];
  float* out = (float*)d_out;

  char* ws = (char*)d_ws;
  unsigned short* wbf = (unsigned short*)(ws + 0);   //  262144 B
  float* qr    = (float*)(ws + 262144);              //  262144 B
  float* gpart = (float*)(ws + 524288);              // 1048576 B
  float* wmix  = (float*)(ws + 1572864);             //   32768 B
  float* xmask = (float*)(ws + 1605632);             //   32768 B (atomic, zeroed)
  float* ctx   = (float*)(ws + 1638400);             //  262144 B (atomic, zeroed)
  float* sp    = (float*)(ws + 1900544);             //  262144 B
  float* P     = (float*)(ws + 2162688);             //   32768 B
  float* Q     = (float*)(ws + 2195456);             //   32768 B
  float* stats = (float*)(ws + 2228224);             //     128 B

  // zero the atomic accumulators (ws is re-poisoned to 0xAA before every launch)
  hipMemsetAsync(ws + 1605632, 0, 32768 + 262144, stream);

  k0_convert<<<512, 256, 0, stream>>>(w_ql, wbf);
  k1_gemm<<<dim3(64, BATCH), 256, 0, stream>>>(x, wbf, w_qr, qr, gpart);
  k2_small<<<BATCH, 256, 0, stream>>>(gpart, b_ql, w_vl, qr, wmix, stats);
  k3_dual<<<dim3(32, 4, BATCH), 256, 0, stream>>>(x, qr, stats, wmix, xmask, ctx);
  k4_tail<<<BATCH, 256, 0, stream>>>(xmask, w_vr, b_vr, w_up, b_up, ln_g, ln_b,
                                     w_red, bn_g, bn_b, bn_rm, bn_rv, w_sel, ctx,
                                     P, Q, sp);
  k5_out<<<BATCH * CIN, 256, 0, stream>>>(x, P, Q, sp, out);
}